// Round 18
// baseline (135.609 us; speedup 1.0000x reference)
//
#include <hip/hip_runtime.h>
#include <hip/hip_bf16.h>

typedef __attribute__((ext_vector_type(8))) short s16x8;
typedef __attribute__((ext_vector_type(4))) short s16x4;
typedef __attribute__((ext_vector_type(4))) float f32x4;

#define SEQ 2048
#define NB 2
#define NH 16
#define HD 64
#define DIM 1024
#define MR (NB * SEQ)
#define NT (SEQ / 64)
#define QSC 0.18033688011112042f /* 0.125 * log2(e): folded into Q so p = exp2(s) */

__device__ __forceinline__ unsigned short f2b(float f) {
    unsigned u = __float_as_uint(f);
    u += 0x7fffu + ((u >> 16) & 1u);
    return (unsigned short)(u >> 16);
}

__device__ __forceinline__ unsigned pk2(float a, float b) {
    unsigned r;
    asm("v_cvt_pk_bf16_f32 %0, %1, %2" : "=v"(r) : "v"(a), "v"(b));
    return r;
}

__device__ __forceinline__ s16x8 mk8(unsigned a, unsigned b, unsigned c, unsigned d) {
    union { unsigned u[4]; s16x8 v; } x;
    x.u[0] = a; x.u[1] = b; x.u[2] = c; x.u[3] = d;
    return x.v;
}

__device__ __forceinline__ s16x8 cat8(s16x4 a, s16x4 b) {
    union { s16x4 h[2]; s16x8 v; } x;
    x.h[0] = a; x.h[1] = b;
    return x.v;
}

__device__ __forceinline__ void gl_lds16(const unsigned short* g, unsigned short* l) {
    __builtin_amdgcn_global_load_lds(
        (const __attribute__((address_space(1))) void*)g,
        (__attribute__((address_space(3))) void*)l, 16, 0, 0);
}

__device__ __forceinline__ unsigned ldsoff(const void* p) {
    return (unsigned)(size_t)(const __attribute__((address_space(3))) void*)p;
}

__device__ __forceinline__ void cast4(const float* __restrict__ src, unsigned short* __restrict__ dst, int i) {
    float4 v = reinterpret_cast<const float4*>(src)[i];
    ushort4 o;
    o.x = f2b(v.x); o.y = f2b(v.y); o.z = f2b(v.z); o.w = f2b(v.w);
    reinterpret_cast<ushort4*>(dst)[i] = o;
}

// One fused prep kernel: casts x,wq,wk,wv,wo to bf16 + builds RoPE cos/sin table.
__global__ __launch_bounds__(256) void prep_kernel(
    const float* __restrict__ x, const float* __restrict__ wq, const float* __restrict__ wk,
    const float* __restrict__ wv, const float* __restrict__ wo,
    unsigned short* __restrict__ xb, unsigned short* __restrict__ wqkv,
    unsigned short* __restrict__ wwo, float2* __restrict__ tab)
{
    int b = blockIdx.x, t = threadIdx.x;
    if (b < 4096)       cast4(x,  xb,                 b * 256 + t);
    else if (b < 5120)  cast4(wq, wqkv,               (b - 4096) * 256 + t);
    else if (b < 6144)  cast4(wk, wqkv + DIM * DIM,   (b - 5120) * 256 + t);
    else if (b < 7168)  cast4(wv, wqkv + 2 * DIM * DIM, (b - 6144) * 256 + t);
    else if (b < 8192)  cast4(wo, wwo,                (b - 7168) * 256 + t);
    else {
        int i = (b - 8192) * 256 + t; // 2048*32 = 65536
        int pos = i >> 5, fi = i & 31;
        float freq = expf((float)fi * (-9.210340371976184f / 32.0f)); // 10000^(-fi/32)
        float emb = (float)pos * freq;
        tab[i] = make_float2(cosf(emb), sinf(emb));
    }
}

// MULTI-WAVE COUNTED-VMCNT GEMM (r15, proven): 128x128 tile, 4 waves, BK=32
// dbuf, raw s_barrier + vmcnt(4) that never drains in-loop. 3 blocks/CU.
template <int EPI>
__global__ __launch_bounds__(256) void gemm_mw(
    const unsigned short* __restrict__ A,
    const unsigned short* __restrict__ Bw,
    const float2* __restrict__ tab,
    unsigned short* __restrict__ qw,
    unsigned short* __restrict__ kw,
    unsigned short* __restrict__ vw,
    float* __restrict__ out,
    const float* __restrict__ bias)
{
    __shared__ unsigned short As[2][4096];
    __shared__ unsigned short Bs[2][4096];
    const int t = threadIdx.x;
    const int wid = t >> 6, lane = t & 63;
    const int wr = wid >> 1, wc = wid & 1;
    const int lo = lane & 15, hi = lane >> 4;
    const int wg = blockIdx.x;
    const int xcd = wg & 7, bi = wg >> 3;
    const int by = xcd * 4 + (bi & 3);
    const int bx = bi >> 2;
    const int m0 = by * 128, n0 = bx * 128;

    const unsigned short* agp = A + (long)(m0 + (t >> 2)) * DIM + (t & 3) * 8;
    const unsigned short* bgp = Bw + (long)(n0 + (t >> 2)) * DIM + (t & 3) * 8;
    unsigned short* alds = &As[0][0] + wid * 512;
    unsigned short* blds = &Bs[0][0] + wid * 512;

#define STG(buf, k0) {                                        \
        gl_lds16(agp + (k0), alds + (buf) * 4096);            \
        gl_lds16(agp + (k0) + 64 * DIM, alds + (buf) * 4096 + 2048); \
        gl_lds16(bgp + (k0), blds + (buf) * 4096);            \
        gl_lds16(bgp + (k0) + 64 * DIM, blds + (buf) * 4096 + 2048); }

    f32x4 acc[4][4] = {};
    STG(0, 0)
    STG(1, 32)

    for (int kt = 0; kt < 32; ++kt) {
        const int cb = kt & 1;
        if (kt < 31) { asm volatile("s_waitcnt vmcnt(4)" ::: "memory"); }
        else         { asm volatile("s_waitcnt vmcnt(0)" ::: "memory"); }
        __builtin_amdgcn_sched_barrier(0);
        __builtin_amdgcn_s_barrier();
        __builtin_amdgcn_sched_barrier(0);
        s16x8 af[4], bf[4];
#pragma unroll
        for (int i = 0; i < 4; ++i)
            af[i] = *reinterpret_cast<const s16x8*>(&As[cb][(wr * 64 + i * 16 + lo) * 32 + hi * 8]);
#pragma unroll
        for (int j = 0; j < 4; ++j)
            bf[j] = *reinterpret_cast<const s16x8*>(&Bs[cb][(wc * 64 + j * 16 + lo) * 32 + hi * 8]);
        asm volatile("s_waitcnt lgkmcnt(0)" ::: "memory");
        __builtin_amdgcn_sched_barrier(0);
        if (kt + 2 < 32) {
            __builtin_amdgcn_s_barrier();
            __builtin_amdgcn_sched_barrier(0);
            STG(cb, (kt + 2) * 32)
        }
        __builtin_amdgcn_s_setprio(1);
#pragma unroll
        for (int i = 0; i < 4; ++i)
#pragma unroll
            for (int j = 0; j < 4; ++j)
                acc[i][j] = __builtin_amdgcn_mfma_f32_16x16x32_bf16(af[i], bf[j], acc[i][j], 0, 0, 0);
        __builtin_amdgcn_s_setprio(0);
    }
#undef STG

    const int rowb = m0 + wr * 64;
    const int colb = n0 + wc * 64;
    if (EPI == 0) {
#pragma unroll
        for (int ai = 0; ai < 4; ++ai) {
#pragma unroll
            for (int cp = 0; cp < 2; ++cp) {
                f32x4 v1 = acc[ai][cp];
                f32x4 v2 = acc[ai][cp + 2];
                int e = colb + cp * 16 + lo;
                int which = e >> 10;
                int eh = e & 1023;
                int h = eh >> 6, d = eh & 63;
                unsigned short* dst = (which == 0) ? qw : ((which == 1) ? kw : vw);
                float qs = (which == 0) ? QSC : 1.0f;
#pragma unroll
                for (int r = 0; r < 4; ++r) {
                    int m = rowb + ai * 16 + hi * 4 + r;
                    int b = m >> 11, pos = m & (SEQ - 1);
                    long off = (((long)(b * NH + h)) * SEQ + pos) * HD;
                    if (which == 2) {
                        dst[off + d]      = f2b(v1[r]);
                        dst[off + d + 32] = f2b(v2[r]);
                    } else {
                        float2 cs = tab[pos * 32 + d];
                        dst[off + d]      = f2b((v1[r] * cs.x - v2[r] * cs.y) * qs);
                        dst[off + d + 32] = f2b((v1[r] * cs.y + v2[r] * cs.x) * qs);
                    }
                }
            }
        }
    } else {
#pragma unroll
        for (int ai = 0; ai < 4; ++ai)
#pragma unroll
            for (int cj = 0; cj < 4; ++cj) {
                int n = colb + cj * 16 + lo;
                float bv = bias[n];
#pragma unroll
                for (int r = 0; r < 4; ++r) {
                    int m = rowb + ai * 16 + hi * 4 + r;
                    out[(long)m * DIM + n] = acc[ai][cj][r] + bv;
                }
            }
    }
}

// 1-WAVE barrier-free GEMM (r14): 64x128 per wave, private dbuf LDS, counted
// vmcnt(12) depth-2, zero barriers. Used for the out-projection.
template <int EPI>
__global__ __launch_bounds__(64, 2) void gemm_async(
    const unsigned short* __restrict__ A,
    const unsigned short* __restrict__ Bw,
    const float2* __restrict__ tab,
    unsigned short* __restrict__ qw,
    unsigned short* __restrict__ kw,
    unsigned short* __restrict__ vw,
    float* __restrict__ out,
    const float* __restrict__ bias)
{
    __shared__ unsigned short As[2 * 2048];
    __shared__ unsigned short Bs[2 * 4096];
    const int lane = threadIdx.x & 63;
    const int lo = lane & 15, hi = lane >> 4;
    const int wg = blockIdx.x;
    const int xcd = wg & 7, bi = wg >> 3;
    const int bx = bi >> 3;
    const int by = xcd * 8 + (bi & 7);
    const int m0 = by * 64, n0 = bx * 128;

    const unsigned short* agp = A + (long)(m0 + (lane >> 2)) * DIM + (lane & 3) * 8;
    const unsigned short* bgp = Bw + (long)(n0 + (lane >> 2)) * DIM + (lane & 3) * 8;

    f32x4 acc[4][8] = {};

#define STG(buf, k0) {                                       \
        unsigned short* al = &As[(buf) * 2048];              \
        unsigned short* bl = &Bs[(buf) * 4096];              \
        _Pragma("unroll") for (int s = 0; s < 4; ++s)        \
            gl_lds16(agp + (k0) + (long)s * 16 * DIM, al + s * 512); \
        _Pragma("unroll") for (int s = 0; s < 8; ++s)        \
            gl_lds16(bgp + (k0) + (long)s * 16 * DIM, bl + s * 512); }

    STG(0, 0)
    STG(1, 32)

    for (int kt = 0; kt < 32; ++kt) {
        const int cb = kt & 1;
        if (kt < 31) { asm volatile("s_waitcnt vmcnt(12)" ::: "memory"); }
        else         { asm volatile("s_waitcnt vmcnt(0)" ::: "memory"); }
        __builtin_amdgcn_sched_barrier(0);
        s16x8 af[4], bf[8];
#pragma unroll
        for (int i = 0; i < 4; ++i)
            af[i] = *reinterpret_cast<const s16x8*>(&As[cb * 2048 + (i * 16 + lo) * 32 + hi * 8]);
#pragma unroll
        for (int j = 0; j < 8; ++j)
            bf[j] = *reinterpret_cast<const s16x8*>(&Bs[cb * 4096 + (j * 16 + lo) * 32 + hi * 8]);
        asm volatile("s_waitcnt lgkmcnt(0)" ::: "memory");
        __builtin_amdgcn_sched_barrier(0);
        if (kt + 2 < 32) STG(cb, (kt + 2) * 32)
        __builtin_amdgcn_sched_barrier(0);
        __builtin_amdgcn_s_setprio(1);
#pragma unroll
        for (int i = 0; i < 4; ++i)
#pragma unroll
            for (int j = 0; j < 8; ++j)
                acc[i][j] = __builtin_amdgcn_mfma_f32_16x16x32_bf16(af[i], bf[j], acc[i][j], 0, 0, 0);
        __builtin_amdgcn_s_setprio(0);
    }
#undef STG

    if (EPI == 1) {
#pragma unroll
        for (int ai = 0; ai < 4; ++ai)
#pragma unroll
            for (int bj = 0; bj < 8; ++bj) {
                int n = n0 + bj * 16 + lo;
                float bv = bias[n];
#pragma unroll
                for (int r = 0; r < 4; ++r) {
                    int m = m0 + ai * 16 + hi * 4 + r;
                    out[(long)m * DIM + n] = acc[ai][bj][r] + bv;
                }
            }
    }
}

// Flash attention, Q-SPLIT (r18): wave w owns q-rows [q0+16w, q0+16w+16).
// K/V staged ONCE per block (shared, dbuf 32KB); accumulator shrinks 4x
// (od[4] = 16 regs: O[64d][16q]); no cross-wave O reduction; each wave writes
// its q-rows directly. Unnormalized softmax (no max/rescale state).
// Sync = r15's counted-vmcnt ladder: vmcnt(4) -> s_barrier -> all reads ->
// lgkm(0) -> s_barrier -> STAGE(t+2) -> compute. Swizzled K (pre-swizzled
// source + XOR read), subtiled V + ds_read_b64_tr_b16, PV at K=32 with the
// cat8 dual-operand permutation over the tile's two 16-k halves.
__global__ __launch_bounds__(256) void flash_attn(
    const unsigned short* __restrict__ qw,
    const unsigned short* __restrict__ kw,
    const unsigned short* __restrict__ vw,
    unsigned short* __restrict__ ao)
{
    __shared__ __align__(16) unsigned char smem[32768]; // 2 bufs x (K 8KB | V 8KB)
    const int t = threadIdx.x;
    const int w = t >> 6, lane = t & 63;
    const int lo = lane & 15, hi = lane >> 4;
    const int wg = blockIdx.x;
    const int swz = (wg & 7) * 128 + (wg >> 3); // XCD-chunked (1024 = 8*128)
    const int bh = swz >> 5;
    const int q0 = (swz & 31) * 64;
    const unsigned short* qh = qw + (long)bh * SEQ * HD;
    const unsigned short* kh = kw + (long)bh * SEQ * HD;
    const unsigned short* vh = vw + (long)bh * SEQ * HD;

    // Q fragments: wave's own 16 rows only (B-operand: Q[q=lo][d=ds*32+hi*8+j])
    s16x8 qf[2];
#pragma unroll
    for (int ds = 0; ds < 2; ++ds)
        qf[ds] = *reinterpret_cast<const s16x8*>(
            qh + (long)(q0 + w * 16 + lo) * HD + ds * 32 + hi * 8);
    asm volatile("s_waitcnt vmcnt(0)" ::: "memory"); // loop vmcnt counts staging only

    // ---- block-wide staging: wave w stages chunks c0=w*64+lane, c1=256+c0 ----
    // K: row = c>>3, slot = c&7, source slot' = slot ^ (row&7) (read un-XORs)
    const int kc0 = w * 64 + lane, kc1 = 256 + kc0;
    const int krow0 = kc0 >> 3, kslot0 = (kc0 & 7) ^ (krow0 & 7);
    const int krow1 = kc1 >> 3, kslot1 = (kc1 & 7) ^ (krow1 & 7);
    const unsigned short* ksrc0 = kh + (long)krow0 * HD + kslot0 * 8;
    const unsigned short* ksrc1 = kh + (long)krow1 * HD + kslot1 * 8;
    // V subtiled: c -> (k,d): k = ((c>>5)<<2)|((c&7)>>1), d = ((c>>3)&3)*16 + (c&1)*8
    const int vk0 = ((kc0 >> 5) << 2) | ((kc0 & 7) >> 1);
    const int vd0 = ((kc0 >> 3) & 3) * 16 + (kc0 & 1) * 8;
    const int vk1 = ((kc1 >> 5) << 2) | ((kc1 & 7) >> 1);
    const int vd1 = ((kc1 >> 3) & 3) * 16 + (kc1 & 1) * 8;
    const unsigned short* vsrc0 = vh + (long)vk0 * HD + vd0;
    const unsigned short* vsrc1 = vh + (long)vk1 * HD + vd1;

    unsigned short* kd0 = (unsigned short*)(smem) + w * 512;          // c0*16B = w*1024+lane*16
    unsigned short* kd1 = (unsigned short*)(smem) + 2048 + w * 512;   // +4096B
    unsigned short* vd0p = (unsigned short*)(smem) + 4096 + w * 512;  // V at +8192B
    unsigned short* vd1p = (unsigned short*)(smem) + 6144 + w * 512;

#define STAGE(buf, kb) {                                   \
        gl_lds16(ksrc0 + (long)(kb) * HD, kd0 + (buf) * 8192); \
        gl_lds16(ksrc1 + (long)(kb) * HD, kd1 + (buf) * 8192); \
        gl_lds16(vsrc0 + (long)(kb) * HD, vd0p + (buf) * 8192); \
        gl_lds16(vsrc1 + (long)(kb) * HD, vd1p + (buf) * 8192); }

    // K read offsets (bytes within buf): row = cj*16+lo, chunk (ds*4+hi)^(lo&7)
    const int kroA = lo * 128 + ((hi ^ (lo & 7)) << 4);        // ds=0
    const int kroB = lo * 128 + (((4 + hi) ^ (lo & 7)) << 4);  // ds=1
    // V tr-read: subtile (krow4 = kk*8 + half*4 + hi, dgrp=dt) at
    // 8192 + krow4*512 + dt*128, lane chunk lo*8
    const unsigned vtb0 = ldsoff(smem) + 8192 + hi * 512 + lo * 8;

    f32x4 od[4] = {}; // od[dt][r]: O[d=dt*16+hi*4+r][q=lo] for wave's q-rows
    float lr = 0.f;   // per-lane partial sum of p over k in {cj*16+hi*4+r}

    STAGE(0, 0)
    STAGE(1, 64)

    for (int kt = 0; kt < NT; ++kt) {
        const int cb = kt & 1;
        if (kt < NT - 1) { asm volatile("s_waitcnt vmcnt(4)" ::: "memory"); }
        else             { asm volatile("s_waitcnt vmcnt(0)" ::: "memory"); }
        __builtin_amdgcn_sched_barrier(0);
        __builtin_amdgcn_s_barrier(); // buf cb fully staged by all waves
        __builtin_amdgcn_sched_barrier(0);

        // ---- all LDS reads for this tile ----
        const unsigned char* bp = smem + cb * 16384;
        s16x8 kf[4][2];
#pragma unroll
        for (int cj = 0; cj < 4; ++cj) {
            kf[cj][0] = *reinterpret_cast<const s16x8*>(bp + cj * 2048 + kroA);
            kf[cj][1] = *reinterpret_cast<const s16x8*>(bp + cj * 2048 + kroB);
        }
        s16x4 vt[2][2][4]; // [kk][half][dt]
#pragma unroll
        for (int kk = 0; kk < 2; ++kk)
#pragma unroll
            for (int half = 0; half < 2; ++half) {
                const unsigned vb = vtb0 + cb * 16384 + kk * 4096 + half * 2048;
                asm volatile("ds_read_b64_tr_b16 %0, %1"            : "=v"(vt[kk][half][0]) : "v"(vb));
                asm volatile("ds_read_b64_tr_b16 %0, %1 offset:128" : "=v"(vt[kk][half][1]) : "v"(vb));
                asm volatile("ds_read_b64_tr_b16 %0, %1 offset:256" : "=v"(vt[kk][half][2]) : "v"(vb));
                asm volatile("ds_read_b64_tr_b16 %0, %1 offset:384" : "=v"(vt[kk][half][3]) : "v"(vb));
            }
        asm volatile("s_waitcnt lgkmcnt(0)" ::: "memory");
        __builtin_amdgcn_sched_barrier(0);
        if (kt + 2 < NT) {
            __builtin_amdgcn_s_barrier(); // all waves done reading buf cb
            __builtin_amdgcn_sched_barrier(0);
            STAGE(cb, (kt + 2) * 64)
        }

        // ---- QK: S^T[k=cj*16+hi*4+r][q=lo], 8 MFMA ----
        f32x4 sc[4] = {};
        __builtin_amdgcn_s_setprio(1);
#pragma unroll
        for (int cj = 0; cj < 4; ++cj)
            sc[cj] = __builtin_amdgcn_mfma_f32_16x16x32_bf16(kf[cj][0], qf[0], sc[cj], 0, 0, 0);
#pragma unroll
        for (int cj = 0; cj < 4; ++cj)
            sc[cj] = __builtin_amdgcn_mfma_f32_16x16x32_bf16(kf[cj][1], qf[1], sc[cj], 0, 0, 0);
        __builtin_amdgcn_s_setprio(0);

        // ---- p = exp2(s); pack P into K=32 B-frags (permuted k-slots) ----
        s16x8 pf8[2];
#pragma unroll
        for (int kk = 0; kk < 2; ++kk) {
            float a0 = exp2f(sc[2 * kk][0]), a1 = exp2f(sc[2 * kk][1]);
            float a2 = exp2f(sc[2 * kk][2]), a3 = exp2f(sc[2 * kk][3]);
            float b0 = exp2f(sc[2 * kk + 1][0]), b1 = exp2f(sc[2 * kk + 1][1]);
            float b2 = exp2f(sc[2 * kk + 1][2]), b3 = exp2f(sc[2 * kk + 1][3]);
            lr += ((a0 + a1) + (a2 + a3)) + ((b0 + b1) + (b2 + b3));
            pf8[kk] = mk8(pk2(a0, a1), pk2(a2, a3), pk2(b0, b1), pk2(b2, b3));
        }

        // ---- PV: od[dt] += V^T chunks x P, 8 MFMA (same k-slot permutation) ----
        __builtin_amdgcn_s_setprio(1);
#pragma unroll
        for (int kk = 0; kk < 2; ++kk) {
#pragma unroll
            for (int dt = 0; dt < 4; ++dt) {
                s16x8 vf8 = cat8(vt[kk][0][dt], vt[kk][1][dt]);
                od[dt] = __builtin_amdgcn_mfma_f32_16x16x32_bf16(vf8, pf8[kk], od[dt], 0, 0, 0);
            }
        }
        __builtin_amdgcn_s_setprio(0);
    }
#undef STAGE

    // ---- epilogue: no cross-wave reduction; finish l and store own q-rows ----
    lr += __shfl_xor(lr, 16);
    lr += __shfl_xor(lr, 32);
    float linv = 1.f / lr;
    const int b = bh >> 4, h = bh & 15;
    const int qg = q0 + w * 16 + lo;
#pragma unroll
    for (int dt = 0; dt < 4; ++dt) {
        uint2 u;
        u.x = pk2(od[dt][0] * linv, od[dt][1] * linv);
        u.y = pk2(od[dt][2] * linv, od[dt][3] * linv);
        *reinterpret_cast<uint2*>(ao + ((long)(b * SEQ + qg)) * DIM + h * 64 + dt * 16 + hi * 4) = u;
    }
}

extern "C" void kernel_launch(void* const* d_in, const int* in_sizes, int n_in,
                              void* d_out, int out_size, void* d_ws, size_t ws_size,
                              hipStream_t stream) {
    const float* x   = (const float*)d_in[0];
    const float* wq  = (const float*)d_in[1];
    const float* wk  = (const float*)d_in[2];
    const float* wv  = (const float*)d_in[3];
    const float* wo  = (const float*)d_in[4];
    const float* wob = (const float*)d_in[5];

    char* ws = (char*)d_ws;
    unsigned short* xb   = (unsigned short*)(ws);             // 8.0 MiB
    unsigned short* wqkv = (unsigned short*)(ws + 8388608);   // 6.0 MiB
    unsigned short* wwo  = (unsigned short*)(ws + 14680064);  // 2.0 MiB
    unsigned short* qw   = (unsigned short*)(ws + 16777216);  // 8.0 MiB
    unsigned short* kw   = (unsigned short*)(ws + 25165824);  // 8.0 MiB
    unsigned short* vw   = (unsigned short*)(ws + 33554432);  // 8.0 MiB
    unsigned short* ao   = (unsigned short*)(ws + 41943040);  // 8.0 MiB
    float2* tab          = (float2*)(ws + 50331648);          // 512 KiB

    prep_kernel<<<8448, 256, 0, stream>>>(x, wq, wk, wv, wo, xb, wqkv, wwo, tab);

    gemm_mw<0><<<768, 256, 0, stream>>>(xb, wqkv, tab, qw, kw, vw, nullptr, nullptr);
    flash_attn<<<1024, 256, 0, stream>>>(qw, kw, vw, ao);
    gemm_async<1><<<512, 64, 0, stream>>>(ao, wwo, nullptr, nullptr, nullptr, nullptr,
                                          (float*)d_out, wob);
}